// Round 1
// baseline (1456.566 us; speedup 1.0000x reference)
//
#include <hip/hip_runtime.h>

// PsRoiOffset fused sparse kernel for MI355X (gfx950).
// Shapes (fixed by the reference): features (1,200,304,196) f32,
// rois (512,4) f32, W_off (3,3,196,392) f32, b_off (392) f32,
// out (512,7,7,4) f32.
//
// Per block = one (roi, bin): the 2x2 sample points need bilinear corners
// drawn from 4 y-candidates x 4 x-candidates = 16 corner positions.
// Each corner needs offset_map at channels g*4..g*4+3, i.e. 8 conv outputs
// (o = g*8..g*8+7), each a 3*3*196 = 1764-long dot product with the feature
// patch, then a deformable bilinear fetch of features at (corner + offset).

constexpr int H = 200, W = 304, C = 196, CO = 392;
constexpr int KK = 7, DIM = 4, NROI = 512;

__global__ __launch_bounds__(256) void psroi_offset_kernel(
    const float* __restrict__ feat, const float* __restrict__ rois,
    const float* __restrict__ Woff, const float* __restrict__ boff,
    float* __restrict__ out)
{
  const int blk = blockIdx.x;
  const int n   = blk / (KK * KK);
  const int bin = blk % (KK * KK);
  const int bi  = bin / KK, bj = bin % KK;
  const int g   = bin;                 // group = bi*7 + bj
  const int tid = threadIdx.x;

  // ---- Phase 1: ROI geometry (redundant per thread; cheap) ----
  const float rx1 = rois[n * 4 + 0] * 0.25f;
  const float ry1 = rois[n * 4 + 1] * 0.25f;
  const float rx2 = rois[n * 4 + 2] * 0.25f;
  const float ry2 = rois[n * 4 + 3] * 0.25f;
  const float bh = (ry2 - ry1) * (1.0f / 7.0f);
  const float bw = (rx2 - rx1) * (1.0f / 7.0f);

  int ycand[4], xcand[4];
  float wy[2], wx[2];
#pragma unroll
  for (int si = 0; si < 2; ++si) {
    float sy = ry1 + ((float)bi + ((float)si + 0.5f) * 0.5f) * bh;
    sy = fminf(fmaxf(sy, 0.0f), (float)(H - 1));
    float fy = floorf(sy);
    wy[si] = sy - fy;
    int i0 = (int)fy;
    ycand[2 * si]     = i0;
    ycand[2 * si + 1] = min(i0 + 1, H - 1);

    float sx = rx1 + ((float)bj + ((float)si + 0.5f) * 0.5f) * bw;
    sx = fminf(fmaxf(sx, 0.0f), (float)(W - 1));
    float fx = floorf(sx);
    wx[si] = sx - fx;
    int j0 = (int)fx;
    xcand[2 * si]     = j0;
    xcand[2 * si + 1] = min(j0 + 1, W - 1);
  }

  __shared__ float om_lds[16][DIM];   // offset_map values per corner

  // ---- Phase 2: conv dots + deformable sample. 16 threads per corner. ----
  const int corner = tid >> 4;        // 0..15  = ycidx*4 + xcidx
  const int lane16 = tid & 15;
  const int yc = ycand[corner >> 2];
  const int xc = xcand[corner & 3];

  float acc[8];
#pragma unroll
  for (int oo = 0; oo < 8; ++oo) acc[oo] = 0.0f;

  const float* wbase = Woff + g * 8;
#pragma unroll
  for (int p = 0; p < 9; ++p) {
    const int dy = p / 3, dx = p % 3;
    const int ys = yc + dy - 1, xs = xc + dx - 1;
    if (ys < 0 || ys >= H || xs < 0 || xs >= W) continue;   // SAME zero-pad
    const float* frow = feat + ((size_t)(ys * W + xs)) * C;
    const float* wrow = wbase + (size_t)p * C * CO;
    for (int ci = lane16; ci < C; ci += 16) {
      const float f  = frow[ci];
      const float4 w0 = *reinterpret_cast<const float4*>(wrow + (size_t)ci * CO);
      const float4 w1 = *reinterpret_cast<const float4*>(wrow + (size_t)ci * CO + 4);
      acc[0] = fmaf(f, w0.x, acc[0]);
      acc[1] = fmaf(f, w0.y, acc[1]);
      acc[2] = fmaf(f, w0.z, acc[2]);
      acc[3] = fmaf(f, w0.w, acc[3]);
      acc[4] = fmaf(f, w1.x, acc[4]);
      acc[5] = fmaf(f, w1.y, acc[5]);
      acc[6] = fmaf(f, w1.z, acc[6]);
      acc[7] = fmaf(f, w1.w, acc[7]);
    }
  }
  // butterfly-reduce the 8 partial dots across the 16-lane group
#pragma unroll
  for (int m = 8; m >= 1; m >>= 1) {
#pragma unroll
    for (int oo = 0; oo < 8; ++oo)
      acc[oo] += __shfl_xor(acc[oo], m, 16);
  }

  if (lane16 < DIM) {
    const int d = lane16;
    const int c = g * DIM + d;
    const float offy = acc[2 * d]     + boff[2 * c];
    const float offx = acc[2 * d + 1] + boff[2 * c + 1];
    float yy = fminf(fmaxf((float)yc + offy, 0.0f), (float)(H - 1));
    float xx = fminf(fmaxf((float)xc + offx, 0.0f), (float)(W - 1));
    float fy = floorf(yy), fx = floorf(xx);
    const float ay = yy - fy, ax = xx - fx;
    const int iy0 = (int)fy, ix0 = (int)fx;
    const int iy1 = min(iy0 + 1, H - 1), ix1 = min(ix0 + 1, W - 1);
    const float v00 = feat[((size_t)(iy0 * W + ix0)) * C + c];
    const float v01 = feat[((size_t)(iy0 * W + ix1)) * C + c];
    const float v10 = feat[((size_t)(iy1 * W + ix0)) * C + c];
    const float v11 = feat[((size_t)(iy1 * W + ix1)) * C + c];
    const float top = v00 + (v01 - v00) * ax;
    const float bot = v10 + (v11 - v10) * ax;
    om_lds[corner][d] = top + (bot - top) * ay;
  }
  __syncthreads();

  // ---- Phase 3: bilinear-combine the 2x2 sample points, mean, store ----
  if (tid < 16) {
    const int si = tid >> 3;          // bit3: y sample
    const int sj = (tid >> 2) & 1;    // bit2: x sample
    const int d  = tid & 3;
    float v = 0.0f;
#pragma unroll
    for (int a = 0; a < 2; ++a) {
#pragma unroll
      for (int b = 0; b < 2; ++b) {
        const float wgt = (a ? wy[si] : 1.0f - wy[si]) *
                          (b ? wx[sj] : 1.0f - wx[sj]);
        v += wgt * om_lds[(2 * si + a) * 4 + (2 * sj + b)][d];
      }
    }
    v += __shfl_xor(v, 4, 16);        // sum over sj
    v += __shfl_xor(v, 8, 16);        // sum over si
    if (tid < 4)
      out[(((size_t)n * KK + bi) * KK + bj) * DIM + tid] = 0.25f * v;
  }
}

extern "C" void kernel_launch(void* const* d_in, const int* in_sizes, int n_in,
                              void* d_out, int out_size, void* d_ws, size_t ws_size,
                              hipStream_t stream) {
  const float* feat = (const float*)d_in[0];
  const float* rois = (const float*)d_in[1];
  const float* Woff = (const float*)d_in[2];
  const float* boff = (const float*)d_in[3];
  float* out = (float*)d_out;

  const int nblocks = NROI * KK * KK;   // 25088
  psroi_offset_kernel<<<dim3(nblocks), dim3(256), 0, stream>>>(
      feat, rois, Woff, boff, out);
}